// Round 17
// baseline (34596.548 us; speedup 1.0000x reference)
//
#include <hip/hip_runtime.h>
#include <hip/hip_bf16.h>

// LSTM_19267223290530 — 2-layer LSTM (B=64,T=1024,IN=128,HID=512) + FC.
// Round 17: layer overlap via NON-cooperative 512-wg launch of a LEAN merged
// kernel. bid 0-255 = L0 (dispatched first), 256-511 = L1. Dependency is
// acyclic (L1 waits on L0 epochs only): if 2 wg/CU co-reside -> overlap
// (serial depth 1025); else HW sequences L1 after L0 (= R16 semantics).
// LDS 81,920B (w_hh 64KB + 16KB half-K stage/red overlay); lambda-free body
// (R15's lambda-fused version hit VGPR 256 + spill; R8's lambda-free
// runtime-L kernel measured 136). All coherent loads wait-inside-asm (R14).

#define NTH 256
#define WPG 64
#define BPG 16
#define HIDDEN 512
#define TSTEPS 1024
#define BATCH 64
#define SPIN_BUDGET 400000000ull   // absolute deadline (~4s): fail, never hang

using bf16 = __hip_bfloat16;

__device__ __forceinline__ float b2fl(unsigned short s) {
  return __uint_as_float(((unsigned int)s) << 16);
}
__device__ __forceinline__ float sigm(float x) { return 1.0f / (1.0f + __expf(-x)); }
__device__ __forceinline__ float tanh_fast(float x) {
  float ax = fabsf(x);
  float e2 = __expf(2.0f * ax);
  float t  = 1.0f - 2.0f / (e2 + 1.0f);
  return copysignf(t, x);
}
__device__ __forceinline__ void fma4(float& a, const float4 w, const float4 h) {
  a = fmaf(w.x, h.x, a);
  a = fmaf(w.y, h.y, a);
  a = fmaf(w.z, h.z, a);
  a = fmaf(w.w, h.w, a);
}
__device__ __forceinline__ void st_cc(float* p, float v) {
  __hip_atomic_store(p, v, __ATOMIC_RELAXED, __HIP_MEMORY_SCOPE_AGENT);
}
__device__ __forceinline__ void st_cu(unsigned* p, unsigned v) {
  __hip_atomic_store(p, v, __ATOMIC_RELAXED, __HIP_MEMORY_SCOPE_AGENT);
}
__device__ __forceinline__ void st_ci(int* p, int v) {
  __hip_atomic_store(p, v, __ATOMIC_RELAXED, __HIP_MEMORY_SCOPE_AGENT);
}
__device__ __forceinline__ int ld_ci(const int* p) {
  return __hip_atomic_load((int*)p, __ATOMIC_RELAXED, __HIP_MEMORY_SCOPE_AGENT);
}
__device__ __forceinline__ void cfence() { asm volatile("" ::: "memory"); }

// Coherent vector loads — wait INSIDE the asm block (R14-proven sound).
__device__ __forceinline__ void ld4f_wait(const float4* q0, const float4* q1,
                                          const float4* q2, const float4* q3,
                                          float4 hv[4]) {
  asm volatile(
      "global_load_dwordx4 %0, %4, off sc0 sc1\n\t"
      "global_load_dwordx4 %1, %5, off sc0 sc1\n\t"
      "global_load_dwordx4 %2, %6, off sc0 sc1\n\t"
      "global_load_dwordx4 %3, %7, off sc0 sc1\n\t"
      "s_waitcnt vmcnt(0)"
      : "=&v"(hv[0]), "=&v"(hv[1]), "=&v"(hv[2]), "=&v"(hv[3])
      : "v"(q0), "v"(q1), "v"(q2), "v"(q3)
      : "memory");
  __builtin_amdgcn_sched_barrier(0);
}
__device__ __forceinline__ void ld2u_wait(const uint4* q0, const uint4* q1,
                                          uint4 sv[2]) {
  asm volatile(
      "global_load_dwordx4 %0, %2, off sc0 sc1\n\t"
      "global_load_dwordx4 %1, %3, off sc0 sc1\n\t"
      "s_waitcnt vmcnt(0)"
      : "=&v"(sv[0]), "=&v"(sv[1])
      : "v"(q0), "v"(q1)
      : "memory");
  __builtin_amdgcn_sched_barrier(0);
}
__device__ __forceinline__ float4 unpk2(unsigned a, unsigned b) {
  return make_float4(b2fl((unsigned short)a), b2fl((unsigned short)(a >> 16)),
                     b2fl((unsigned short)b), b2fl((unsigned short)(b >> 16)));
}

// ---------------------------------------------------------------------------
// Merged dual-layer scan, one wg = one layer-slice. grid 512 x 256.
// L = bid>>8; lb = bid&255; g = lb&3 (batches [16g,16g+16)); w = lb>>2
// (units [8w,8w+8)). LDS: wv4 [32][128]f4 (64KB) + stg 4096f (16KB) = 81,920B.
// Chain c = L*4+g: flags bars[c*64+w]; epoch bars[512+c*16]. L1 step t gates
// on ep(L0,g) >= t+1. Straight-line body, no lambdas (VGPR hygiene).
// ---------------------------------------------------------------------------
__global__ __launch_bounds__(NTH, 1)
void lstm_merged(const float* __restrict__ xin,
                 const float* __restrict__ wih0, const float* __restrict__ whh0,
                 const float* __restrict__ bih0, const float* __restrict__ bhh0,
                 const float* __restrict__ wih1, const float* __restrict__ whh1,
                 const float* __restrict__ bih1, const float* __restrict__ bhh1,
                 float* __restrict__ hbuf0,     // [2][64][512]
                 float* __restrict__ hbuf1,     // [2][64][512]
                 unsigned* __restrict__ sequ,   // [64][1024][256] packed 2xbf16
                 int* __restrict__ bars)
{
  const int tid = threadIdx.x, bid = blockIdx.x;
  const int L  = bid >> 8;
  const int lb = bid & 255;
  const int g  = lb & 3, w = lb >> 2;
  const int b0g = g * BPG, u0 = w * 8;

  const float* wih = L ? wih1 : wih0;
  const float* whh = L ? whh1 : whh0;
  const float* bih = L ? bih1 : bih0;
  const float* bhh = L ? bhh1 : bhh0;
  float* hb = L ? hbuf1 : hbuf0;
  const int DIN = L ? 512 : 128;

  extern __shared__ float lds[];
  float4* wv4  = (float4*)lds;            // [32][128] w_hh slice, swizzled
  float*  stg  = lds + 4 * 32 * 128;      // 4096 f: half-K stage / red overlay
  float4* stg4 = (float4*)stg;
  float*  red  = stg;

  const int chain = L * 4 + g;
  int* fl   = bars + chain * 64;
  int* ep   = bars + 512 + chain * 16;
  int* ep0g = bars + 512 + g * 16;        // L0 epoch, same batch group
  const unsigned long long deadline =
      __builtin_amdgcn_s_memrealtime() + SPIN_BUDGET;

  // ---- w_hh slice -> LDS (XOR swizzle) ----
  for (int idx = tid; idx < 32 * 128; idx += NTH) {
    int r = idx >> 7, c4 = idx & 127, sw = (r >> 2) & 7;
    int grow = (r >> 3) * HIDDEN + u0 + (r & 7);
    wv4[r * 128 + (c4 ^ sw)] = *(const float4*)(whh + (size_t)grow * HIDDEN + c4 * 4);
  }
  const int rr = tid & 7, bb = (tid >> 3) & 3, kc = tid >> 5;
  const float* wx[4];
#pragma unroll
  for (int j = 0; j < 4; ++j) {
    int r = 4 * rr + j;
    int grow = (r >> 3) * HIDDEN + u0 + (r & 7);
    wx[j] = wih + (size_t)grow * DIN;
  }
  // ---- bias (4 scalars) + c-state in registers; thread tid<128 owns (bl,lu) ----
  const int lu = tid & 7, bl = tid >> 3;
  float bi_ = 0.f, bf_ = 0.f, bg_ = 0.f, bo_ = 0.f, creg = 0.f;
  if (tid < 128) {
    bi_ = bih[0 * HIDDEN + u0 + lu] + bhh[0 * HIDDEN + u0 + lu];
    bf_ = bih[1 * HIDDEN + u0 + lu] + bhh[1 * HIDDEN + u0 + lu];
    bg_ = bih[2 * HIDDEN + u0 + lu] + bhh[2 * HIDDEN + u0 + lu];
    bo_ = bih[3 * HIDDEN + u0 + lu] + bhh[3 * HIDDEN + u0 + lu];
  }
  __syncthreads();

  for (int t = 0; t < TSTEPS; ++t) {
    float acc[4][4];
#pragma unroll
    for (int j = 0; j < 4; ++j)
#pragma unroll
      for (int i = 0; i < 4; ++i) acc[j][i] = 0.0f;

    if (L == 0) {
      // ---- stage x(t) ([16][32]f4 front of stg), cached loads ----
#pragma unroll
      for (int n = 0; n < 2; ++n) {
        int idx = tid + n * NTH, b = idx >> 5, c4 = idx & 31;
        float4 v = *(const float4*)(xin + ((size_t)(b0g + b) * TSTEPS + t) * 128 + c4 * 4);
        stg4[b * 32 + (c4 ^ (b >> 2))] = v;
      }
      __syncthreads();
      // ---- xpart K=128 (w_ih0 streamed from L2) ----
#pragma unroll
      for (int kk = 0; kk < 4; ++kk) {
        int k4 = kc * 4 + kk;
        float4 wq[4], xq[4];
#pragma unroll
        for (int j = 0; j < 4; ++j) wq[j] = *(const float4*)(wx[j] + k4 * 4);
#pragma unroll
        for (int i = 0; i < 4; ++i) {
          int b = 4 * bb + i;
          xq[i] = stg4[b * 32 + (k4 ^ bb)];
        }
#pragma unroll
        for (int j = 0; j < 4; ++j)
#pragma unroll
          for (int i = 0; i < 4; ++i) fma4(acc[j][i], wq[j], xq[i]);
      }
      // ---- wait own epoch: h(t-1) ready ----
      if (t > 0) {
        while (ld_ci(ep) < t) {
          if (__builtin_amdgcn_s_memrealtime() > deadline) break;
          __builtin_amdgcn_s_sleep(1);
        }
        cfence();
      }
      __syncthreads();          // x reads done before h overwrites stg
    } else {
      // ---- gate on L0: seq(t) complete ----
      {
        while (ld_ci(ep0g) < t + 1) {
          if (__builtin_amdgcn_s_memrealtime() > deadline) break;
          __builtin_amdgcn_s_sleep(1);
        }
        cfence();
      }
      // ---- x = seq(t), JIT half staging + xpart per half ----
#pragma unroll
      for (int h = 0; h < 2; ++h) {
        {
          uint4 sv[2];
          int i0 = tid, i1 = tid + NTH;
          int bA = i0 >> 5, qA = i0 & 31;
          int bB = i1 >> 5, qB = i1 & 31;
          const uint4* pA = (const uint4*)(sequ + ((size_t)(b0g + bA) * TSTEPS + t) * 256) + h * 32 + qA;
          const uint4* pB = (const uint4*)(sequ + ((size_t)(b0g + bB) * TSTEPS + t) * 256) + h * 32 + qB;
          ld2u_wait(pA, pB, sv);
          int kA = bA >> 2, kB = bB >> 2;
          stg4[bA * 64 + ((2 * qA) ^ kA)]     = unpk2(sv[0].x, sv[0].y);
          stg4[bA * 64 + ((2 * qA + 1) ^ kA)] = unpk2(sv[0].z, sv[0].w);
          stg4[bB * 64 + ((2 * qB) ^ kB)]     = unpk2(sv[1].x, sv[1].y);
          stg4[bB * 64 + ((2 * qB + 1) ^ kB)] = unpk2(sv[1].z, sv[1].w);
        }
        __syncthreads();        // half ready
#pragma unroll
        for (int kk = 0; kk < 8; ++kk) {
          int lk = kc * 8 + kk;
          float4 wq[4], xq[4];
#pragma unroll
          for (int j = 0; j < 4; ++j) wq[j] = *(const float4*)(wx[j] + (h * 64 + lk) * 4);
#pragma unroll
          for (int i = 0; i < 4; ++i) {
            int b = 4 * bb + i;
            xq[i] = stg4[b * 64 + (lk ^ bb)];
          }
#pragma unroll
          for (int j = 0; j < 4; ++j)
#pragma unroll
            for (int i = 0; i < 4; ++i) fma4(acc[j][i], wq[j], xq[i]);
        }
        __syncthreads();        // half reads done before overwrite
      }
      // ---- wait own epoch: h(t-1) ready ----
      if (t > 0) {
        while (ld_ci(ep) < t) {
          if (__builtin_amdgcn_s_memrealtime() > deadline) break;
          __builtin_amdgcn_s_sleep(1);
        }
        cfence();
      }
    }

    // ---- h(t-1): JIT half staging + hcomp per half (both layers) ----
    const float* hbase = hb + (size_t)(t & 1) * (BATCH * HIDDEN)
                         + (size_t)b0g * HIDDEN;
#pragma unroll
    for (int h = 0; h < 2; ++h) {
      if (t == 0) {
        float4 z = make_float4(0.f, 0.f, 0.f, 0.f);
#pragma unroll
        for (int n = 0; n < 4; ++n) stg4[tid + n * NTH] = z;
      } else {
        const float4* b4 = (const float4*)hbase;
        int i0 = tid, i1 = tid + NTH, i2 = tid + 2 * NTH, i3 = tid + 3 * NTH;
        const float4* p0 = b4 + (i0 >> 6) * 128 + h * 64 + (i0 & 63);
        const float4* p1 = b4 + (i1 >> 6) * 128 + h * 64 + (i1 & 63);
        const float4* p2 = b4 + (i2 >> 6) * 128 + h * 64 + (i2 & 63);
        const float4* p3 = b4 + (i3 >> 6) * 128 + h * 64 + (i3 & 63);
        float4 hv[4];
        ld4f_wait(p0, p1, p2, p3, hv);
        stg4[(i0 >> 6) * 64 + ((i0 & 63) ^ (i0 >> 8))] = hv[0];
        stg4[(i1 >> 6) * 64 + ((i1 & 63) ^ (i1 >> 8))] = hv[1];
        stg4[(i2 >> 6) * 64 + ((i2 & 63) ^ (i2 >> 8))] = hv[2];
        stg4[(i3 >> 6) * 64 + ((i3 & 63) ^ (i3 >> 8))] = hv[3];
      }
      __syncthreads();          // half ready
#pragma unroll
      for (int kk = 0; kk < 8; ++kk) {
        int lk = kc * 8 + kk;
        float4 wq[4], hq[4];
#pragma unroll
        for (int j = 0; j < 4; ++j) wq[j] = wv4[(4 * rr + j) * 128 + h * 64 + (lk ^ rr)];
#pragma unroll
        for (int i = 0; i < 4; ++i) {
          int b = 4 * bb + i;
          hq[i] = stg4[b * 64 + (lk ^ bb)];
        }
#pragma unroll
        for (int j = 0; j < 4; ++j)
#pragma unroll
          for (int i = 0; i < 4; ++i) fma4(acc[j][i], wq[j], hq[i]);
      }
      __syncthreads();          // half reads done before overwrite
    }

    // ---- K-split reduction (red overlays stg; same-thread alias safe) ----
#pragma unroll
    for (int j = 0; j < 4; ++j)
#pragma unroll
      for (int i = 0; i < 4; ++i)
        red[kc * 512 + (4 * rr + j) * 16 + 4 * bb + i] = acc[j][i];
    __syncthreads();
    {
      const int a0 = tid, a1 = tid + 256;
      float s0 = 0.f, s1 = 0.f;
#pragma unroll
      for (int k2 = 0; k2 < 8; ++k2) {
        s0 += red[k2 * 512 + a0];
        s1 += red[k2 * 512 + a1];
      }
      red[a0] = s0;   // only this thread touches column a0/a1
      red[a1] = s1;
    }
    __syncthreads();

    // ---- gates (tid<128 owns (bl,lu)); bias + c in registers ----
    if (tid < 128) {
      float gi = red[(0  + lu) * 16 + bl] + bi_;
      float gf = red[(8  + lu) * 16 + bl] + bf_;
      float gg = red[(16 + lu) * 16 + bl] + bg_;
      float go = red[(24 + lu) * 16 + bl] + bo_;
      float iv = sigm(gi), fv = sigm(gf), gv = tanh_fast(gg), ov = sigm(go);
      float c = fv * creg + iv * gv;
      creg = c;
      float hn = ov * tanh_fast(c);
      st_cc(hb + (size_t)((t + 1) & 1) * (BATCH * HIDDEN)
            + (size_t)(b0g + bl) * HIDDEN + u0 + lu, hn);
      if (L == 0) {
        float other = __shfl_xor(hn, 1);
        if ((lu & 1) == 0) {
          bf16 lo = __float2bfloat16(hn), hi = __float2bfloat16(other);
          unsigned pv = (unsigned)(*(unsigned short*)&lo) |
                        ((unsigned)(*(unsigned short*)&hi) << 16);
          st_cu(sequ + ((size_t)(b0g + bl) * TSTEPS + t) * 256 + ((u0 + lu) >> 1), pv);
        }
      }
    }
    __syncthreads();            // drains vmcnt: stores device-visible
    if (tid == 0) st_ci(&fl[w], t + 1);
    cfence();
    if (w == 0 && tid < WPG) {  // gatherer: 64 flags -> 1 epoch word
      while (true) {
        int v = ld_ci(&fl[tid]);
        if (__all(v >= t + 1)) break;
        if (__builtin_amdgcn_s_memrealtime() > deadline) break;
        __builtin_amdgcn_s_sleep(1);
      }
      if (tid == 0) st_ci(ep, t + 1);
    }
  }
}

// ---------------------------------------------------------------------------
// FC: out[b][o] = dot(h2[b], fc_w[o]) + fc_b[o]. h2 = hbuf1 buffer 0.
// ---------------------------------------------------------------------------
__global__ __launch_bounds__(NTH, 1)
void fc_kernel(const float* __restrict__ h2, const float* __restrict__ fcw,
               const float* __restrict__ fcb, float* __restrict__ out)
{
  extern __shared__ float lds[];
  float4* fw4 = (float4*)lds;
  float4* h24 = fw4 + 64 * 128;
  const int tid = threadIdx.x;
  const int bq  = blockIdx.x;

  for (int idx = tid; idx < 64 * 128; idx += NTH) {
    int o = idx >> 7, c4 = idx & 127;
    fw4[o * 128 + (c4 ^ (o & 7))] = *(const float4*)(fcw + (size_t)o * HIDDEN + c4 * 4);
  }
  for (int idx = tid; idx < 8 * 128; idx += NTH) {
    int b = idx >> 7, c4 = idx & 127;
    h24[b * 128 + c4] = *(const float4*)(h2 + (size_t)(bq * 8 + b) * HIDDEN + c4 * 4);
  }
  __syncthreads();

  const int o = tid & 63, bs = tid >> 6;
  float a0 = 0.f, a1 = 0.f;
  for (int c4 = 0; c4 < 128; ++c4) {
    float4 wv = fw4[o * 128 + (c4 ^ (o & 7))];
    float4 h0 = h24[(2 * bs) * 128 + c4];
    float4 h1 = h24[(2 * bs + 1) * 128 + c4];
    fma4(a0, wv, h0);
    fma4(a1, wv, h1);
  }
  const float bo = fcb[o];
  out[(size_t)(bq * 8 + 2 * bs) * 64 + o]     = a0 + bo;
  out[(size_t)(bq * 8 + 2 * bs + 1) * 64 + o] = a1 + bo;
}

__global__ void init_ws(float* hbuf0, float* hbuf1, int* bars)
{
  int i = blockIdx.x * blockDim.x + threadIdx.x;
  if (i < 2 * BATCH * HIDDEN) { hbuf0[i] = 0.f; hbuf1[i] = 0.f; }
  if (i < 1024) bars[i] = 0;
}

// ---------------------------------------------------------------------------
extern "C" void kernel_launch(void* const* d_in, const int* in_sizes, int n_in,
                              void* d_out, int out_size, void* d_ws, size_t ws_size,
                              hipStream_t stream)
{
  const float* x    = (const float*)d_in[0];
  const float* wih0 = (const float*)d_in[1];
  const float* whh0 = (const float*)d_in[2];
  const float* bih0 = (const float*)d_in[3];
  const float* bhh0 = (const float*)d_in[4];
  const float* wih1 = (const float*)d_in[5];
  const float* whh1 = (const float*)d_in[6];
  const float* bih1 = (const float*)d_in[7];
  const float* bhh1 = (const float*)d_in[8];
  const float* fcw  = (const float*)d_in[9];
  const float* fcb  = (const float*)d_in[10];
  float* out = (float*)d_out;

  // ws: bars 1024 int | hbuf0 [2][64][512] | hbuf1 same | sequ [64][1024][256]
  float*    wsf   = (float*)d_ws;
  int*      bars  = (int*)d_ws;
  float*    hbuf0 = wsf + 1024;
  float*    hbuf1 = hbuf0 + 2 * BATCH * HIDDEN;
  unsigned* sequ  = (unsigned*)(hbuf1 + 2 * BATCH * HIDDEN);

  const size_t ldsS  = (size_t)(32 * 128) * 16 + (size_t)4096 * 4;   // 81,920 B
  const size_t ldsfc = (size_t)(64 * 128 + 8 * 128) * 16;

  hipLaunchKernelGGL(init_ws, dim3(256), dim3(256), 0, stream, hbuf0, hbuf1, bars);

  hipFuncSetAttribute((const void*)lstm_merged,
                      hipFuncAttributeMaxDynamicSharedMemorySize, (int)ldsS);
  // Plain (non-cooperative) 512-wg launch. L0 wgs (bid 0-255) dispatch first;
  // dependency L1->L0 is acyclic, so co-residency gives overlap and
  // insufficient residency degrades to hardware-sequenced R16 semantics.
  hipLaunchKernelGGL(lstm_merged, dim3(512), dim3(NTH), ldsS, stream,
                     x, wih0, whh0, bih0, bhh0, wih1, whh1, bih1, bhh1,
                     hbuf0, hbuf1, sequ, bars);

  hipFuncSetAttribute((const void*)fc_kernel,
                      hipFuncAttributeMaxDynamicSharedMemorySize, (int)ldsfc);
  hipLaunchKernelGGL(fc_kernel, dim3(8), dim3(NTH), ldsfc, stream, hbuf1, fcw, fcb, out);
}

// Round 18
// 18010.976 us; speedup vs baseline: 1.9209x; 1.9209x over previous
//
#include <hip/hip_runtime.h>
#include <hip/hip_bf16.h>

// LSTM_19267223290530 — 2-layer LSTM (B=64,T=1024,IN=128,HID=512) + FC.
// Round 18 (FINAL): restore Round-16 kernel — the measured best (18.34 ms).
// Structure: two sequential persistent scan kernels (templated per layer,
// VGPR 60), 256 wgs x 256 thr, 4 batch-groups x 64 wgs; relaxed agent-scope
// flag->gatherer->epoch barrier; coherent dwordx4 h-exchange (wait inside
// asm); padded K-split reduction (bank conflicts -40%).
// Layer-fusion/co-residency variants (R6-R15, R17) all lost: merged bodies
// pin VGPR at 256 with scratch spill; templated split kernels stay lean.

#define NTH 256
#define WPG 64      // workgroups per barrier group
#define NGRP 4      // batch groups
#define BPG 16      // batches per group
#define UPW 8       // hidden units per wg
#define RPW 32      // gate rows per wg (4*UPW)
#define HIDDEN 512
#define TSTEPS 1024
#define BATCH 64

// spin budget: ABSOLUTE deadline per kernel (~4s at 100MHz s_memrealtime).
#define SPIN_BUDGET 400000000ull

using bf16 = __hip_bfloat16;

__device__ __forceinline__ float b2fl(unsigned short s) {
  return __uint_as_float(((unsigned int)s) << 16);
}

template<typename T> struct Ld4;
template<> struct Ld4<float> {
  static __device__ __forceinline__ float4 go(const float* p) { return *(const float4*)p; }
};
template<> struct Ld4<bf16> {
  static __device__ __forceinline__ float4 go(const bf16* p) {
    ushort4 v = *(const ushort4*)p;
    return make_float4(b2fl(v.x), b2fl(v.y), b2fl(v.z), b2fl(v.w));
  }
};

template<typename T> __device__ __forceinline__ T to_xout(float f);
template<> __device__ __forceinline__ float to_xout<float>(float f) { return f; }
template<> __device__ __forceinline__ bf16 to_xout<bf16>(float f) { return __float2bfloat16(f); }

__device__ __forceinline__ float sigm(float x) { return 1.0f / (1.0f + __expf(-x)); }
__device__ __forceinline__ float tanh_fast(float x) {
  float ax = fabsf(x);
  float e2 = __expf(2.0f * ax);
  float t  = 1.0f - 2.0f / (e2 + 1.0f);
  return copysignf(t, x);
}
__device__ __forceinline__ void fma4(float& a, const float4 w, const float4 h) {
  a = fmaf(w.x, h.x, a);
  a = fmaf(w.y, h.y, a);
  a = fmaf(w.z, h.z, a);
  a = fmaf(w.w, h.w, a);
}

// coherent (device-visible, no cache maintenance) scalar ops — R4-proven
__device__ __forceinline__ void st_cc(float* p, float v) {
  __hip_atomic_store(p, v, __ATOMIC_RELAXED, __HIP_MEMORY_SCOPE_AGENT);
}
__device__ __forceinline__ void st_ci(int* p, int v) {
  __hip_atomic_store(p, v, __ATOMIC_RELAXED, __HIP_MEMORY_SCOPE_AGENT);
}
__device__ __forceinline__ int ld_ci(const int* p) {
  return __hip_atomic_load((int*)p, __ATOMIC_RELAXED, __HIP_MEMORY_SCOPE_AGENT);
}
__device__ __forceinline__ void cfence() { asm volatile("" ::: "memory"); }

// 8x coherent dwordx4 load, single asm block, wait INSIDE the block (sound).
__device__ __forceinline__ void ld_h8(const float4* base, int tid, float4 hv[8]) {
  const float4* p0 = base + tid;
  const float4* p1 = base + tid + 1 * NTH;
  const float4* p2 = base + tid + 2 * NTH;
  const float4* p3 = base + tid + 3 * NTH;
  const float4* p4 = base + tid + 4 * NTH;
  const float4* p5 = base + tid + 5 * NTH;
  const float4* p6 = base + tid + 6 * NTH;
  const float4* p7 = base + tid + 7 * NTH;
  asm volatile(
      "global_load_dwordx4 %0, %8, off sc0 sc1\n\t"
      "global_load_dwordx4 %1, %9, off sc0 sc1\n\t"
      "global_load_dwordx4 %2, %10, off sc0 sc1\n\t"
      "global_load_dwordx4 %3, %11, off sc0 sc1\n\t"
      "global_load_dwordx4 %4, %12, off sc0 sc1\n\t"
      "global_load_dwordx4 %5, %13, off sc0 sc1\n\t"
      "global_load_dwordx4 %6, %14, off sc0 sc1\n\t"
      "global_load_dwordx4 %7, %15, off sc0 sc1\n\t"
      "s_waitcnt vmcnt(0)"
      : "=&v"(hv[0]), "=&v"(hv[1]), "=&v"(hv[2]), "=&v"(hv[3]),
        "=&v"(hv[4]), "=&v"(hv[5]), "=&v"(hv[6]), "=&v"(hv[7])
      : "v"(p0), "v"(p1), "v"(p2), "v"(p3), "v"(p4), "v"(p5), "v"(p6), "v"(p7)
      : "memory");
  __builtin_amdgcn_sched_barrier(0);
}

// ---------------------------------------------------------------------------
// Persistent LSTM scan (R10 topology). grid = 256 wgs x 256 thr, 1 wg/CU.
// group g = bid&3 owns batches [16g,16g+16); wg w = bid>>2 owns units [8w,8w+8).
// Barrier: flags[g*64+w] -> gatherer (w==0 wave0) -> epoch word -> broadcast.
// ---------------------------------------------------------------------------
template<int D_IN, bool WRITE_SEQ, typename XIN, typename XOUT>
__global__ __launch_bounds__(NTH, 1)
void lstm_scan(const XIN* __restrict__ xin,
               const float* __restrict__ w_ih,
               const float* __restrict__ w_hh,
               const float* __restrict__ b_ih,
               const float* __restrict__ b_hh,
               float* __restrict__ hbuf,        // [2][64][512]
               XOUT* __restrict__ seqout,       // [64][1024][512] (WRITE_SEQ)
               int* __restrict__ barbase)       // 512 ints for this layer
{
  constexpr int D4 = D_IN / 4;
  constexpr bool XW_LDS = (D_IN <= 128);        // layer0: w_ih fits LDS
  constexpr int S4 = 128 + (XW_LDS ? D4 : 0);   // wv row stride (float4)
  constexpr int XC = D_IN / 8;                  // x K-chunk per kc
  constexpr int LD4 = (D_IN == 128) ? 5 : 7;
  constexpr int XPT = (BPG * D4) / NTH;         // x float4 per thread (L0:2, L1:8)

  extern __shared__ float lds[];
  float4* wv4 = (float4*)lds;                   // [RPW][S4] swizzled
  float4* hs4 = wv4 + RPW * S4;                 // [BPG][128] swizzled
  float4* xs4 = hs4 + BPG * 128;                // [BPG][D4]  swizzled
  float*  red = (float*)(xs4 + BPG * D4);       // [8][32*18] padded partials;
                                                // front 512 doubles as gbuf
  float*  bsum = red + 8 * 576;                 // [32]
  float*  cst  = bsum + RPW;                    // [16][8] c-state

  const int tid = threadIdx.x;
  const int bid = blockIdx.x;
  const int g   = bid & 3;
  const int w   = bid >> 2;
  const int b0g = g * BPG;
  const int u0  = w * UPW;
  int* flags = barbase + g * 64;                // arrival flags, monotone
  int* epoch = barbase + 320 + g * 16;          // single release word per group

  const unsigned long long deadline =
      __builtin_amdgcn_s_memrealtime() + SPIN_BUDGET;   // GLOBAL bail

  // ---- weights -> LDS (XOR swizzle) ----
  for (int idx = tid; idx < RPW * S4; idx += NTH) {
    int r  = idx / S4;
    int c4 = idx - r * S4;
    int swz = (r >> 2) & 7;
    int grow = ((r >> 3) * HIDDEN) + u0 + (r & 7);
    if (c4 < 128) {
      float4 v = *(const float4*)(w_hh + (size_t)grow * HIDDEN + c4 * 4);
      wv4[r * S4 + (c4 ^ swz)] = v;
    } else {
      int c4x = c4 - 128;
      float4 v = *(const float4*)(w_ih + (size_t)grow * D_IN + c4x * 4);
      wv4[r * S4 + 128 + (c4x ^ swz)] = v;
    }
  }
  if (tid < RPW) {
    int grow = ((tid >> 3) * HIDDEN) + u0 + (tid & 7);
    bsum[tid] = b_ih[grow] + b_hh[grow];
  }
  if (tid < UPW * BPG) cst[tid] = 0.0f;

  const int rr = tid & 7;          // row quad
  const int bb = (tid >> 3) & 3;   // batch quad
  const int kc = tid >> 5;         // K chunk 0..7

  const float* wxg[4];             // layer1: x-weight rows stream from L2
  if (!XW_LDS) {
#pragma unroll
    for (int j = 0; j < 4; ++j) {
      int r = 4 * rr + j;
      int grow = ((r >> 3) * HIDDEN) + u0 + (r & 7);
      wxg[j] = w_ih + (size_t)grow * D_IN;
    }
  }
  __syncthreads();

  for (int t = 0; t < TSTEPS; ++t) {
    const float* hsrc = hbuf + (size_t)(t & 1) * (BATCH * HIDDEN);
    float*       hdst = hbuf + (size_t)((t + 1) & 1) * (BATCH * HIDDEN);

    // ---- stage x[t] -> LDS (barrier-independent) ----
#pragma unroll
    for (int n = 0; n < XPT; ++n) {
      int idx = tid + n * NTH;
      int b = idx >> LD4, c4 = idx & (D4 - 1);
      float4 v = Ld4<XIN>::go(xin + ((size_t)(b0g + b) * TSTEPS + t) * D_IN + c4 * 4);
      xs4[b * D4 + (c4 ^ (b >> 2))] = v;
    }
    __syncthreads();   // xs4 ready

    float acc[4][4];
#pragma unroll
    for (int j = 0; j < 4; ++j)
#pragma unroll
      for (int i = 0; i < 4; ++i) acc[j][i] = 0.0f;

    // ---- X-PART first (epoch hop hides under this) ----
#pragma unroll 2
    for (int kk = 0; kk < XC / 4; ++kk) {
      const int k4 = kc * (XC / 4) + kk;
      float4 wq[4], xq[4];
      if constexpr (XW_LDS) {
#pragma unroll
        for (int j = 0; j < 4; ++j) wq[j] = wv4[(4 * rr + j) * S4 + 128 + (k4 ^ rr)];
      } else {
#pragma unroll
        for (int j = 0; j < 4; ++j) wq[j] = *(const float4*)(wxg[j] + k4 * 4);
      }
#pragma unroll
      for (int i = 0; i < 4; ++i) xq[i] = xs4[(4 * bb + i) * D4 + (k4 ^ bb)];
#pragma unroll
      for (int j = 0; j < 4; ++j)
#pragma unroll
        for (int i = 0; i < 4; ++i) fma4(acc[j][i], wq[j], xq[i]);
    }

    // ---- wait for h(t-1): all threads poll ONE epoch word (broadcast) ----
    if (t > 0) {
      while (ld_ci(epoch) < t) {
        if (__builtin_amdgcn_s_memrealtime() > deadline) break;  // bounded bail
        __builtin_amdgcn_s_sleep(1);
      }
      cfence();   // forbid hoisting the h loads above the poll
    }

    // ---- h(t-1): 8x dwordx4 coherent load (one asm block, waits inside) ----
    {
      float4 hv[8];
      ld_h8((const float4*)(hsrc + (size_t)b0g * HIDDEN), tid, hv);
#pragma unroll
      for (int n = 0; n < 8; ++n) {
        int idx = tid + n * NTH;
        int b = idx >> 7, c4 = idx & 127;
        hs4[b * 128 + (c4 ^ (b >> 2))] = hv[n];
      }
    }
    __syncthreads();   // hs4 ready

    // ---- H-PART: K chunk [kc*64, kc*64+64) ----
#pragma unroll 4
    for (int kk = 0; kk < 16; ++kk) {
      const int k4 = kc * 16 + kk;
      float4 wq[4], hq[4];
#pragma unroll
      for (int j = 0; j < 4; ++j) wq[j] = wv4[(4 * rr + j) * S4 + (k4 ^ rr)];
#pragma unroll
      for (int i = 0; i < 4; ++i) hq[i] = hs4[(4 * bb + i) * 128 + (k4 ^ bb)];
#pragma unroll
      for (int j = 0; j < 4; ++j)
#pragma unroll
        for (int i = 0; i < 4; ++i) fma4(acc[j][i], wq[j], hq[i]);
    }

    // ---- K-split reduction (PADDED rows: stride 18 kills 8-way conflict) ----
#pragma unroll
    for (int j = 0; j < 4; ++j)
#pragma unroll
      for (int i = 0; i < 4; ++i)
        red[kc * 576 + (4 * rr + j) * 18 + 4 * bb + i] = acc[j][i];
    __syncthreads();
    {
      const int r0 = tid >> 4, c0 = tid & 15;   // a0 = tid      -> row r0
      const int r1 = r0 + 16;                   // a1 = tid+256  -> row r1
      float s0 = bsum[r0], s1 = bsum[r1];
#pragma unroll
      for (int k2 = 0; k2 < 8; ++k2) {
        s0 += red[k2 * 576 + r0 * 18 + c0];
        s1 += red[k2 * 576 + r1 * 18 + c0];
      }
      __syncthreads();   // padded-layout reads done before gbuf overlay write
      red[tid] = s0;             // gbuf linear [32][16]
      red[tid + 256] = s1;
    }
    __syncthreads();

    // ---- gates / state update ----
    if (tid < UPW * BPG) {
      const int lu = tid & 7, bl = tid >> 3;
      float gi = red[(0  + lu) * 16 + bl];
      float gf = red[(8  + lu) * 16 + bl];
      float gg = red[(16 + lu) * 16 + bl];
      float go = red[(24 + lu) * 16 + bl];
      float iv = sigm(gi), fv = sigm(gf), gv = tanh_fast(gg), ov = sigm(go);
      float c = fv * cst[tid] + iv * gv;
      cst[tid] = c;
      float hn = ov * tanh_fast(c);
      const int b = b0g + bl, u = u0 + lu;
      st_cc(hdst + (size_t)b * HIDDEN + u, hn);       // coherent write-through
      if constexpr (WRITE_SEQ)
        seqout[((size_t)b * TSTEPS + t) * HIDDEN + u] = to_xout<XOUT>(hn);
    }

    // ---- arrival + release (two-hop barrier) ----
    __syncthreads();   // drains vmcnt: h stores device-visible before flag
    if (tid == 0)
      st_ci(&flags[w], t + 1);
    cfence();
    if (w == 0 && tid < WPG) {   // wg0 wave0: gather arrivals, publish epoch
      while (true) {
        int v = ld_ci(&flags[tid]);
        if (__all(v >= t + 1)) break;
        if (__builtin_amdgcn_s_memrealtime() > deadline) break;  // bounded bail
        __builtin_amdgcn_s_sleep(1);
      }
      if (tid == 0) st_ci(epoch, t + 1);
    }
    // no trailing __syncthreads: LDS reuse safe (pre-flag sync covers reads).
  }
}

// ---------------------------------------------------------------------------
// FC: out[b][o] = dot(h2[b], fc_w[o]) + fc_b[o].  grid 8, block 256.
// ---------------------------------------------------------------------------
__global__ __launch_bounds__(NTH, 1)
void fc_kernel(const float* __restrict__ h2, const float* __restrict__ fcw,
               const float* __restrict__ fcb, float* __restrict__ out)
{
  extern __shared__ float lds[];
  float4* fw4 = (float4*)lds;          // [64][128] swizzled
  float4* h24 = fw4 + 64 * 128;        // [8][128]
  const int tid = threadIdx.x;
  const int bq  = blockIdx.x;

  for (int idx = tid; idx < 64 * 128; idx += NTH) {
    int o = idx >> 7, c4 = idx & 127;
    fw4[o * 128 + (c4 ^ (o & 7))] = *(const float4*)(fcw + (size_t)o * HIDDEN + c4 * 4);
  }
  for (int idx = tid; idx < 8 * 128; idx += NTH) {
    int b = idx >> 7, c4 = idx & 127;
    h24[b * 128 + c4] = *(const float4*)(h2 + (size_t)(bq * 8 + b) * HIDDEN + c4 * 4);
  }
  __syncthreads();

  const int o = tid & 63, bs = tid >> 6;
  float a0 = 0.f, a1 = 0.f;
  for (int c4 = 0; c4 < 128; ++c4) {
    float4 wv = fw4[o * 128 + (c4 ^ (o & 7))];
    float4 h0 = h24[(2 * bs) * 128 + c4];
    float4 h1 = h24[(2 * bs + 1) * 128 + c4];
    fma4(a0, wv, h0);
    fma4(a1, wv, h1);
  }
  const float bo = fcb[o];
  out[(size_t)(bq * 8 + 2 * bs) * 64 + o]     = a0 + bo;
  out[(size_t)(bq * 8 + 2 * bs + 1) * 64 + o] = a1 + bo;
}

__global__ void init_ws(float* hbuf0, float* hbuf1, int* bars)
{
  int i = blockIdx.x * blockDim.x + threadIdx.x;
  if (i < 2 * BATCH * HIDDEN) { hbuf0[i] = 0.f; hbuf1[i] = 0.f; }
  if (i < 1024) bars[i] = 0;
}

// ---------------------------------------------------------------------------
extern "C" void kernel_launch(void* const* d_in, const int* in_sizes, int n_in,
                              void* d_out, int out_size, void* d_ws, size_t ws_size,
                              hipStream_t stream)
{
  const float* x    = (const float*)d_in[0];
  const float* wih0 = (const float*)d_in[1];
  const float* whh0 = (const float*)d_in[2];
  const float* bih0 = (const float*)d_in[3];
  const float* bhh0 = (const float*)d_in[4];
  const float* wih1 = (const float*)d_in[5];
  const float* whh1 = (const float*)d_in[6];
  const float* bih1 = (const float*)d_in[7];
  const float* bhh1 = (const float*)d_in[8];
  const float* fcw  = (const float*)d_in[9];
  const float* fcb  = (const float*)d_in[10];
  float* out = (float*)d_out;

  // ws layout: bars 1024 int | hbuf0 | hbuf1 | seq
  float* wsf   = (float*)d_ws;
  int*   bars  = (int*)d_ws;                 // 1024 ints: L0 [0..511], L1 [512..1023]
  float* hbuf0 = wsf + 1024;
  float* hbuf1 = hbuf0 + 2 * BATCH * HIDDEN;
  float* seqf  = hbuf1 + 2 * BATCH * HIDDEN;
  const size_t seq_elems = (size_t)BATCH * TSTEPS * HIDDEN;
  const size_t base_bytes = (1024 + 4 * BATCH * HIDDEN) * 4;
  const bool f32seq = ws_size >= base_bytes + seq_elems * 4;

  // LDS sizes (bytes)
  const size_t lds0  = (size_t)((RPW * 160 + BPG * 128 + BPG * 32) * 4 + 8 * 576 + RPW + 128) * 4;
  const size_t lds1  = (size_t)((RPW * 128 + BPG * 128 + BPG * 128) * 4 + 8 * 576 + RPW + 128) * 4;
  const size_t ldsfc = (size_t)(64 * 128 + 8 * 128) * 16;

  hipLaunchKernelGGL(init_ws, dim3(256), dim3(256), 0, stream, hbuf0, hbuf1, bars);

  int* bar0 = bars;
  int* bar1 = bars + 512;
  float* dummy = nullptr;

  if (f32seq) {
    auto* k0 = lstm_scan<128, true,  float, float>;
    auto* k1 = lstm_scan<512, false, float, float>;
    hipFuncSetAttribute((const void*)k0, hipFuncAttributeMaxDynamicSharedMemorySize, (int)lds0);
    hipFuncSetAttribute((const void*)k1, hipFuncAttributeMaxDynamicSharedMemorySize, (int)lds1);
    float* seqp = seqf;
    void* a0[] = { (void*)&x,    (void*)&wih0, (void*)&whh0, (void*)&bih0, (void*)&bhh0,
                   (void*)&hbuf0, (void*)&seqp, (void*)&bar0 };
    if (hipLaunchCooperativeKernel((const void*)k0, dim3(NGRP * WPG), dim3(NTH), a0,
                                   (unsigned)lds0, stream) != hipSuccess) {
      lstm_scan<128, true, float, float><<<dim3(NGRP * WPG), dim3(NTH), lds0, stream>>>(
          x, wih0, whh0, bih0, bhh0, hbuf0, seqp, bar0);
    }
    const float* seqc = seqf;
    void* a1[] = { (void*)&seqc, (void*)&wih1, (void*)&whh1, (void*)&bih1, (void*)&bhh1,
                   (void*)&hbuf1, (void*)&dummy, (void*)&bar1 };
    if (hipLaunchCooperativeKernel((const void*)k1, dim3(NGRP * WPG), dim3(NTH), a1,
                                   (unsigned)lds1, stream) != hipSuccess) {
      lstm_scan<512, false, float, float><<<dim3(NGRP * WPG), dim3(NTH), lds1, stream>>>(
          seqc, wih1, whh1, bih1, bhh1, hbuf1, dummy, bar1);
    }
  } else {
    auto* k0 = lstm_scan<128, true,  float, bf16>;
    auto* k1 = lstm_scan<512, false, bf16, float>;
    hipFuncSetAttribute((const void*)k0, hipFuncAttributeMaxDynamicSharedMemorySize, (int)lds0);
    hipFuncSetAttribute((const void*)k1, hipFuncAttributeMaxDynamicSharedMemorySize, (int)lds1);
    bf16* seqb = (bf16*)seqf;
    void* a0[] = { (void*)&x,    (void*)&wih0, (void*)&whh0, (void*)&bih0, (void*)&bhh0,
                   (void*)&hbuf0, (void*)&seqb, (void*)&bar0 };
    if (hipLaunchCooperativeKernel((const void*)k0, dim3(NGRP * WPG), dim3(NTH), a0,
                                   (unsigned)lds0, stream) != hipSuccess) {
      lstm_scan<128, true, float, bf16><<<dim3(NGRP * WPG), dim3(NTH), lds0, stream>>>(
          x, wih0, whh0, bih0, bhh0, hbuf0, seqb, bar0);
    }
    const bf16* seqc = (const bf16*)seqf;
    void* a1[] = { (void*)&seqc, (void*)&wih1, (void*)&whh1, (void*)&bih1, (void*)&bhh1,
                   (void*)&hbuf1, (void*)&dummy, (void*)&bar1 };
    if (hipLaunchCooperativeKernel((const void*)k1, dim3(NGRP * WPG), dim3(NTH), a1,
                                   (unsigned)lds1, stream) != hipSuccess) {
      lstm_scan<512, false, bf16, float><<<dim3(NGRP * WPG), dim3(NTH), lds1, stream>>>(
          seqc, wih1, whh1, bih1, bhh1, hbuf1, dummy, bar1);
    }
  }

  hipFuncSetAttribute((const void*)fc_kernel, hipFuncAttributeMaxDynamicSharedMemorySize, (int)ldsfc);
  hipLaunchKernelGGL(fc_kernel, dim3(8), dim3(NTH), ldsfc, stream, hbuf1, fcw, fcb, out);
}